// Round 4
// baseline (297.082 us; speedup 1.0000x reference)
//
#include <hip/hip_runtime.h>

#define Bc 2
#define Gc 8
#define Dc 32
#define Hc 128
#define Wc 160
#define HW (Hc * Wc)         // 20480
#define DHW (Dc * HW)        // 655360

// Fused tiling: one block = one (b, d, 32x40 output tile).
// sim computed with reflect halo R=4 into LDS, aggregation reads LDS only.
#define TH 32
#define TW 40
#define R  4
#define SH (TH + 2 * R)      // 40
#define SW (TW + 2 * R)      // 48
#define SIMN (SH * SW)       // 1920
#define NQ (SIMN / 4)        // 480 float4-quads
#define QPR (SW / 4)         // 12 quads per sim-tile row

// Occupancy: round-3 measured VGPR=208 (compiler pipelining) -> 2 waves/SIMD,
// 31% VALUBusy, latency-bound. amdgpu_waves_per_eu(4) caps VGPR at 128
// (natural live set ~90: xv[8]=32 + acc1[8]=32 + misc), doubling occupancy.
// Do NOT use __launch_bounds__ 2nd arg: round-2 showed it clamps to 84 -> spill.
__global__ __launch_bounds__(256) __attribute__((amdgpu_waves_per_eu(4)))
void fused_kernel(
    const float* __restrict__ x1, const float* __restrict__ offset,
    const float* __restrict__ weight,
    const float* __restrict__ w0, const float* __restrict__ s0, const float* __restrict__ b0,
    const float* __restrict__ w1, const float* __restrict__ s1, const float* __restrict__ b1,
    const float* __restrict__ wsim, const float* __restrict__ bsim,
    float* __restrict__ out)
{
    __shared__ __align__(16) float sms[SIMN];  // sim tile with halo
    __shared__ float smw[289];                 // folded MLP weights
    const int tid = threadIdx.x;

    // stage BN-folded weights
    for (int i = tid; i < 289; i += 256) {
        float v;
        if (i < 128)      v = w0[i] * s0[i >> 3];                 // w0f[o][g]
        else if (i < 144) v = b0[i - 128];
        else if (i < 272) v = w1[i - 144] * s1[(i - 144) >> 4];   // w1f[c][o]
        else if (i < 280) v = b1[i - 272];
        else if (i < 288) v = wsim[i - 280];
        else              v = bsim[0];
        smw[i] = v;
    }

    // blk = b*512 + tile*32 + d  (d innermost: consecutive blocks share the
    // offset/weight tile in L2; tile-neighbors are +32/+128 blocks = same XCD)
    const int blk = blockIdx.x;              // 1024 blocks
    const int d   = blk & 31;
    const int t   = (blk >> 5) & 15;
    const int b   = blk >> 9;
    const int h0t = (t >> 2) * TH;
    const int w0t = (t & 3) * TW;

    __syncthreads();

    const float* sw0 = smw;
    const float* sb0 = smw + 128;
    const float* sw1 = smw + 144;
    const float* sb1 = smw + 272;
    const float* sws = smw + 280;
    const float  sbs = smw[288];

    const float* xb = x1 + (size_t)b * (Gc * DHW) + (size_t)d * HW;

    // ---- phase 1: MLP 8->16->8->1 into the LDS sim tile (incl. reflect halo)
#pragma unroll 1
    for (int q = tid; q < NQ; q += 256) {
        const int ty  = q / QPR;
        const int tx0 = (q - ty * QPR) * 4;
        int gh = h0t - R + ty;
        gh = gh < 0 ? -gh : (gh >= Hc ? 2 * Hc - 2 - gh : gh);
        const int gw0 = w0t - R + tx0;

        float4 xv[Gc];
        if (gw0 >= 0 && gw0 <= Wc - 4) {
            // fast path: contiguous, 16B-aligned (w0t,tx0 multiples of 4)
            const float* p = xb + gh * Wc + gw0;
#pragma unroll
            for (int g = 0; g < Gc; ++g)
                xv[g] = *reinterpret_cast<const float4*>(p + g * DHW);
        } else {
            // reflected (reversed) edge quad: 4 scalar gathers per g
            int gw[4];
#pragma unroll
            for (int j = 0; j < 4; ++j) {
                int x = gw0 + j;
                gw[j] = x < 0 ? -x : (x >= Wc ? 2 * Wc - 2 - x : x);
            }
            const float* p = xb + gh * Wc;
#pragma unroll
            for (int g = 0; g < Gc; ++g) {
                xv[g].x = p[g * DHW + gw[0]];
                xv[g].y = p[g * DHW + gw[1]];
                xv[g].z = p[g * DHW + gw[2]];
                xv[g].w = p[g * DHW + gw[3]];
            }
        }

        // layer-1 accumulators, seeded with bias1 (8 x float4 = 32 regs)
        float4 acc1[8];
#pragma unroll
        for (int c = 0; c < 8; ++c) {
            const float bb = sb1[c];
            acc1[c].x = bb; acc1[c].y = bb; acc1[c].z = bb; acc1[c].w = bb;
        }

        // layer 0 fused into layer 1: each h0[o] is consumed immediately,
        // never materialized as an array -> no 64-reg h0 live set.
#pragma unroll
        for (int o = 0; o < 16; ++o) {
            float ax = sb0[o], ay = ax, az = ax, aw = ax;
#pragma unroll
            for (int g = 0; g < Gc; ++g) {
                const float wv = sw0[o * Gc + g];
                ax = fmaf(wv, xv[g].x, ax);
                ay = fmaf(wv, xv[g].y, ay);
                az = fmaf(wv, xv[g].z, az);
                aw = fmaf(wv, xv[g].w, aw);
            }
            ax = fmaxf(ax, 0.f);
            ay = fmaxf(ay, 0.f);
            az = fmaxf(az, 0.f);
            aw = fmaxf(aw, 0.f);
#pragma unroll
            for (int c = 0; c < 8; ++c) {
                const float wv = sw1[c * 16 + o];
                acc1[c].x = fmaf(wv, ax, acc1[c].x);
                acc1[c].y = fmaf(wv, ay, acc1[c].y);
                acc1[c].z = fmaf(wv, az, acc1[c].z);
                acc1[c].w = fmaf(wv, aw, acc1[c].w);
            }
        }

        // sim projection 8 -> 1
        float sx = sbs, sy = sbs, sz = sbs, sw = sbs;
#pragma unroll
        for (int c = 0; c < 8; ++c) {
            const float ws = sws[c];
            sx = fmaf(ws, fmaxf(acc1[c].x, 0.f), sx);
            sy = fmaf(ws, fmaxf(acc1[c].y, 0.f), sy);
            sz = fmaf(ws, fmaxf(acc1[c].z, 0.f), sz);
            sw = fmaf(ws, fmaxf(acc1[c].w, 0.f), sw);
        }

        float4 r; r.x = sx; r.y = sy; r.z = sz; r.w = sw;
        // q*4 == ty*SW + tx0 : aligned float4 LDS store, conflict-free
        *reinterpret_cast<float4*>(&sms[q * 4]) = r;
    }

    __syncthreads();

    // ---- phase 2: 9-neighbor aggregation, dilations 2 (narrow) & 4 (wide)
    const float* offb = offset + (size_t)b * 18 * HW;
    const float* wtb  = weight + (size_t)b * HW;
    float* outb = out + (size_t)(b * Dc + d) * HW;

#pragma unroll 1
    for (int k = 0; k < 5; ++k) {           // 5*256 = 1280 = TH*TW exactly
        const int idx = k * 256 + tid;
        const int oy  = idx / TW;
        const int ox  = idx - oy * TW;
        const int hw  = (h0t + oy) * Wc + (w0t + ox);

        float off[18];
#pragma unroll
        for (int s = 0; s < 18; ++s)
            off[s] = offb[s * HW + hw];
        const float wt = wtb[hw] * 0.5f;

        const float* sp = sms + (oy + R) * SW + (ox + R);
        float a = 0.f;
#pragma unroll
        for (int s = 0; s < 9; ++s) {
            const int dy = s / 3 - 1, dx = s % 3 - 1;
            a = fmaf(off[s + 9], sp[(dy * 2) * SW + dx * 2],
                fmaf(off[s],     sp[(dy * 4) * SW + dx * 4], a));
        }
        outb[hw] = a * wt;
    }
}

extern "C" void kernel_launch(void* const* d_in, const int* in_sizes, int n_in,
                              void* d_out, int out_size, void* d_ws, size_t ws_size,
                              hipStream_t stream)
{
    const float* x1     = (const float*)d_in[0];
    const float* offset = (const float*)d_in[1];
    const float* weight = (const float*)d_in[2];
    const float* w0     = (const float*)d_in[3];
    const float* s0     = (const float*)d_in[4];
    const float* b0     = (const float*)d_in[5];
    const float* w1     = (const float*)d_in[6];
    const float* s1     = (const float*)d_in[7];
    const float* b1     = (const float*)d_in[8];
    const float* wsim   = (const float*)d_in[9];
    const float* bsim   = (const float*)d_in[10];
    float* out = (float*)d_out;

    // B(2) * 16 tiles * D(32) = 1024 blocks, one fused pass, no workspace
    fused_kernel<<<1024, 256, 0, stream>>>(x1, offset, weight,
                                           w0, s0, b0, w1, s1, b1, wsim, bsim,
                                           out);
}

// Round 5
// 205.215 us; speedup vs baseline: 1.4477x; 1.4477x over previous
//
#include <hip/hip_runtime.h>

#define Bc 2
#define Gc 8
#define Dc 32
#define Hc 128
#define Wc 160
#define HW (Hc * Wc)         // 20480
#define DHW (Dc * HW)        // 655360

// Fused tiling: one block = one (b, d, 32x40 output tile).
// sim computed with reflect halo R=4 into LDS, aggregation reads LDS only.
#define TH 32
#define TW 40
#define R  4
#define SH (TH + 2 * R)      // 40
#define SW (TW + 2 * R)      // 48
#define SIMN (SH * SW)       // 1920
#define NQ (SIMN / 4)        // 480 float4-quads
#define QPR (SW / 4)         // 12 quads per sim-tile row

// Occupancy-cap calibration on this toolchain (measured):
//   __launch_bounds__(256,3)    -> 84 VGPR  (256/3)  -> spill, 400 MB scratch
//   amdgpu_waves_per_eu(4)      -> 64 VGPR  (256/4)  -> spill, 600 MB scratch
//   no hint                     -> 208 VGPR -> no spill, but 2 waves/SIMD, 31% VALUBusy
// Law: cap = 256/min_waves. Target cap 128 (occupancy step at 4 waves/SIMD,
// natural live set ~90-110: xv[8]=32 + acc1[8]=32 + addressing) -> min_waves=2.
__global__ __launch_bounds__(256, 2)
void fused_kernel(
    const float* __restrict__ x1, const float* __restrict__ offset,
    const float* __restrict__ weight,
    const float* __restrict__ w0, const float* __restrict__ s0, const float* __restrict__ b0,
    const float* __restrict__ w1, const float* __restrict__ s1, const float* __restrict__ b1,
    const float* __restrict__ wsim, const float* __restrict__ bsim,
    float* __restrict__ out)
{
    __shared__ __align__(16) float sms[SIMN];  // sim tile with halo
    __shared__ float smw[289];                 // folded MLP weights
    const int tid = threadIdx.x;

    // stage BN-folded weights
    for (int i = tid; i < 289; i += 256) {
        float v;
        if (i < 128)      v = w0[i] * s0[i >> 3];                 // w0f[o][g]
        else if (i < 144) v = b0[i - 128];
        else if (i < 272) v = w1[i - 144] * s1[(i - 144) >> 4];   // w1f[c][o]
        else if (i < 280) v = b1[i - 272];
        else if (i < 288) v = wsim[i - 280];
        else              v = bsim[0];
        smw[i] = v;
    }

    // blk = b*512 + tile*32 + d  (d innermost: consecutive blocks share the
    // offset/weight tile in L2; tile-neighbors are +32/+128 blocks = same XCD)
    const int blk = blockIdx.x;              // 1024 blocks
    const int d   = blk & 31;
    const int t   = (blk >> 5) & 15;
    const int b   = blk >> 9;
    const int h0t = (t >> 2) * TH;
    const int w0t = (t & 3) * TW;

    __syncthreads();

    const float* sw0 = smw;
    const float* sb0 = smw + 128;
    const float* sw1 = smw + 144;
    const float* sb1 = smw + 272;
    const float* sws = smw + 280;
    const float  sbs = smw[288];

    const float* xb = x1 + (size_t)b * (Gc * DHW) + (size_t)d * HW;

    // ---- phase 1: MLP 8->16->8->1 into the LDS sim tile (incl. reflect halo)
#pragma unroll 1
    for (int q = tid; q < NQ; q += 256) {
        const int ty  = q / QPR;
        const int tx0 = (q - ty * QPR) * 4;
        int gh = h0t - R + ty;
        gh = gh < 0 ? -gh : (gh >= Hc ? 2 * Hc - 2 - gh : gh);
        const int gw0 = w0t - R + tx0;

        float4 xv[Gc];
        if (gw0 >= 0 && gw0 <= Wc - 4) {
            // fast path: contiguous, 16B-aligned (w0t,tx0 multiples of 4)
            const float* p = xb + gh * Wc + gw0;
#pragma unroll
            for (int g = 0; g < Gc; ++g)
                xv[g] = *reinterpret_cast<const float4*>(p + g * DHW);
        } else {
            // reflected (reversed) edge quad: 4 scalar gathers per g
            int gw[4];
#pragma unroll
            for (int j = 0; j < 4; ++j) {
                int x = gw0 + j;
                gw[j] = x < 0 ? -x : (x >= Wc ? 2 * Wc - 2 - x : x);
            }
            const float* p = xb + gh * Wc;
#pragma unroll
            for (int g = 0; g < Gc; ++g) {
                xv[g].x = p[g * DHW + gw[0]];
                xv[g].y = p[g * DHW + gw[1]];
                xv[g].z = p[g * DHW + gw[2]];
                xv[g].w = p[g * DHW + gw[3]];
            }
        }

        // layer-1 accumulators, seeded with bias1 (8 x float4 = 32 regs)
        float4 acc1[8];
#pragma unroll
        for (int c = 0; c < 8; ++c) {
            const float bb = sb1[c];
            acc1[c].x = bb; acc1[c].y = bb; acc1[c].z = bb; acc1[c].w = bb;
        }

        // layer 0 fused into layer 1: each h0[o] is consumed immediately,
        // never materialized as an array -> no 64-reg h0 live set.
#pragma unroll
        for (int o = 0; o < 16; ++o) {
            float ax = sb0[o], ay = ax, az = ax, aw = ax;
#pragma unroll
            for (int g = 0; g < Gc; ++g) {
                const float wv = sw0[o * Gc + g];
                ax = fmaf(wv, xv[g].x, ax);
                ay = fmaf(wv, xv[g].y, ay);
                az = fmaf(wv, xv[g].z, az);
                aw = fmaf(wv, xv[g].w, aw);
            }
            ax = fmaxf(ax, 0.f);
            ay = fmaxf(ay, 0.f);
            az = fmaxf(az, 0.f);
            aw = fmaxf(aw, 0.f);
#pragma unroll
            for (int c = 0; c < 8; ++c) {
                const float wv = sw1[c * 16 + o];
                acc1[c].x = fmaf(wv, ax, acc1[c].x);
                acc1[c].y = fmaf(wv, ay, acc1[c].y);
                acc1[c].z = fmaf(wv, az, acc1[c].z);
                acc1[c].w = fmaf(wv, aw, acc1[c].w);
            }
        }

        // sim projection 8 -> 1
        float sx = sbs, sy = sbs, sz = sbs, sw = sbs;
#pragma unroll
        for (int c = 0; c < 8; ++c) {
            const float ws = sws[c];
            sx = fmaf(ws, fmaxf(acc1[c].x, 0.f), sx);
            sy = fmaf(ws, fmaxf(acc1[c].y, 0.f), sy);
            sz = fmaf(ws, fmaxf(acc1[c].z, 0.f), sz);
            sw = fmaf(ws, fmaxf(acc1[c].w, 0.f), sw);
        }

        float4 r; r.x = sx; r.y = sy; r.z = sz; r.w = sw;
        // q*4 == ty*SW + tx0 : aligned float4 LDS store, conflict-free
        *reinterpret_cast<float4*>(&sms[q * 4]) = r;
    }

    __syncthreads();

    // ---- phase 2: 9-neighbor aggregation, dilations 2 (narrow) & 4 (wide)
    const float* offb = offset + (size_t)b * 18 * HW;
    const float* wtb  = weight + (size_t)b * HW;
    float* outb = out + (size_t)(b * Dc + d) * HW;

#pragma unroll 1
    for (int k = 0; k < 5; ++k) {           // 5*256 = 1280 = TH*TW exactly
        const int idx = k * 256 + tid;
        const int oy  = idx / TW;
        const int ox  = idx - oy * TW;
        const int hw  = (h0t + oy) * Wc + (w0t + ox);

        float off[18];
#pragma unroll
        for (int s = 0; s < 18; ++s)
            off[s] = offb[s * HW + hw];
        const float wt = wtb[hw] * 0.5f;

        const float* sp = sms + (oy + R) * SW + (ox + R);
        float a = 0.f;
#pragma unroll
        for (int s = 0; s < 9; ++s) {
            const int dy = s / 3 - 1, dx = s % 3 - 1;
            a = fmaf(off[s + 9], sp[(dy * 2) * SW + dx * 2],
                fmaf(off[s],     sp[(dy * 4) * SW + dx * 4], a));
        }
        outb[hw] = a * wt;
    }
}

extern "C" void kernel_launch(void* const* d_in, const int* in_sizes, int n_in,
                              void* d_out, int out_size, void* d_ws, size_t ws_size,
                              hipStream_t stream)
{
    const float* x1     = (const float*)d_in[0];
    const float* offset = (const float*)d_in[1];
    const float* weight = (const float*)d_in[2];
    const float* w0     = (const float*)d_in[3];
    const float* s0     = (const float*)d_in[4];
    const float* b0     = (const float*)d_in[5];
    const float* w1     = (const float*)d_in[6];
    const float* s1     = (const float*)d_in[7];
    const float* b1     = (const float*)d_in[8];
    const float* wsim   = (const float*)d_in[9];
    const float* bsim   = (const float*)d_in[10];
    float* out = (float*)d_out;

    // B(2) * 16 tiles * D(32) = 1024 blocks, one fused pass, no workspace
    fused_kernel<<<1024, 256, 0, stream>>>(x1, offset, weight,
                                           w0, s0, b0, w1, s1, b1, wsim, bsim,
                                           out);
}

// Round 6
// 122.002 us; speedup vs baseline: 2.4351x; 1.6821x over previous
//
#include <hip/hip_runtime.h>

#define Bc 2
#define Gc 8
#define Dc 32
#define Hc 128
#define Wc 160
#define HW (Hc * Wc)         // 20480
#define DHW (Dc * HW)        // 655360

// Fused tiling: one block = one (b, d, 32x40 output tile).
// sim computed with reflect halo R=4 into LDS, aggregation reads LDS only.
#define TH 32
#define TW 40
#define R  4
#define SH (TH + 2 * R)      // 40
#define SW (TW + 2 * R)      // 48
#define SIMN (SH * SW)       // 1920
#define NQ (SIMN / 4)        // 480 float4-quads
#define QPR (SW / 4)         // 12 quads per sim-tile row

// Register-pressure history (measured):
//   caps 84/64/128 (LB(256,3), waves_per_eu(4), LB(256,2)) -> ALL spill
//     (compiler's pipelined live set >128; it spills rather than de-pipelines)
//   no cap + q-loop (R3)      -> 208 VGPR, no spill, 2 waves/SIMD, 31% VALUBusy
// Fix: remove the q-loop entirely. 512 threads = one quad per thread in
// phase 1 (straight-line body -> no cross-iteration pipelining incentive
// -> natural VGPR ~100-130). NO cap: caps proved strictly harmful here.
__global__ __launch_bounds__(512)
void fused_kernel(
    const float* __restrict__ x1, const float* __restrict__ offset,
    const float* __restrict__ weight,
    const float* __restrict__ w0, const float* __restrict__ s0, const float* __restrict__ b0,
    const float* __restrict__ w1, const float* __restrict__ s1, const float* __restrict__ b1,
    const float* __restrict__ wsim, const float* __restrict__ bsim,
    float* __restrict__ out)
{
    __shared__ __align__(16) float sms[SIMN];  // sim tile with halo
    __shared__ float smw[289];                 // folded MLP weights
    const int tid = threadIdx.x;

    // stage BN-folded weights (single pass, tid<289)
    if (tid < 289) {
        const int i = tid;
        float v;
        if (i < 128)      v = w0[i] * s0[i >> 3];                 // w0f[o][g]
        else if (i < 144) v = b0[i - 128];
        else if (i < 272) v = w1[i - 144] * s1[(i - 144) >> 4];   // w1f[c][o]
        else if (i < 280) v = b1[i - 272];
        else if (i < 288) v = wsim[i - 280];
        else              v = bsim[0];
        smw[i] = v;
    }

    // blk = b*512 + tile*32 + d  (d innermost: consecutive blocks share the
    // offset/weight tile in L2; tile-neighbors are +32/+128 blocks = same XCD)
    const int blk = blockIdx.x;              // 1024 blocks
    const int d   = blk & 31;
    const int t   = (blk >> 5) & 15;
    const int b   = blk >> 9;
    const int h0t = (t >> 2) * TH;
    const int w0t = (t & 3) * TW;

    __syncthreads();

    const float* sw0 = smw;
    const float* sb0 = smw + 128;
    const float* sw1 = smw + 144;
    const float* sb1 = smw + 272;
    const float* sws = smw + 280;
    const float  sbs = smw[288];

    const float* xb = x1 + (size_t)b * (Gc * DHW) + (size_t)d * HW;

    // ---- phase 1: MLP 8->16->8->1 into the LDS sim tile (incl. reflect halo)
    // ONE quad per thread, straight-line (tid 480..511 idle through to barrier)
    if (tid < NQ) {
        const int q   = tid;
        const int ty  = q / QPR;
        const int tx0 = (q - ty * QPR) * 4;
        int gh = h0t - R + ty;
        gh = gh < 0 ? -gh : (gh >= Hc ? 2 * Hc - 2 - gh : gh);
        const int gw0 = w0t - R + tx0;

        float4 xv[Gc];
        if (gw0 >= 0 && gw0 <= Wc - 4) {
            // fast path: contiguous, 16B-aligned (w0t,tx0 multiples of 4)
            const float* p = xb + gh * Wc + gw0;
#pragma unroll
            for (int g = 0; g < Gc; ++g)
                xv[g] = *reinterpret_cast<const float4*>(p + g * DHW);
        } else {
            // reflected (reversed) edge quad: 4 scalar gathers per g
            int gw[4];
#pragma unroll
            for (int j = 0; j < 4; ++j) {
                int x = gw0 + j;
                gw[j] = x < 0 ? -x : (x >= Wc ? 2 * Wc - 2 - x : x);
            }
            const float* p = xb + gh * Wc;
#pragma unroll
            for (int g = 0; g < Gc; ++g) {
                xv[g].x = p[g * DHW + gw[0]];
                xv[g].y = p[g * DHW + gw[1]];
                xv[g].z = p[g * DHW + gw[2]];
                xv[g].w = p[g * DHW + gw[3]];
            }
        }

        // layer-1 accumulators, seeded with bias1 (8 x float4 = 32 regs)
        float4 acc1[8];
#pragma unroll
        for (int c = 0; c < 8; ++c) {
            const float bb = sb1[c];
            acc1[c].x = bb; acc1[c].y = bb; acc1[c].z = bb; acc1[c].w = bb;
        }

        // layer 0 fused into layer 1: each h0[o] consumed immediately
#pragma unroll
        for (int o = 0; o < 16; ++o) {
            float ax = sb0[o], ay = ax, az = ax, aw = ax;
#pragma unroll
            for (int g = 0; g < Gc; ++g) {
                const float wv = sw0[o * Gc + g];
                ax = fmaf(wv, xv[g].x, ax);
                ay = fmaf(wv, xv[g].y, ay);
                az = fmaf(wv, xv[g].z, az);
                aw = fmaf(wv, xv[g].w, aw);
            }
            ax = fmaxf(ax, 0.f);
            ay = fmaxf(ay, 0.f);
            az = fmaxf(az, 0.f);
            aw = fmaxf(aw, 0.f);
#pragma unroll
            for (int c = 0; c < 8; ++c) {
                const float wv = sw1[c * 16 + o];
                acc1[c].x = fmaf(wv, ax, acc1[c].x);
                acc1[c].y = fmaf(wv, ay, acc1[c].y);
                acc1[c].z = fmaf(wv, az, acc1[c].z);
                acc1[c].w = fmaf(wv, aw, acc1[c].w);
            }
        }

        // sim projection 8 -> 1
        float sx = sbs, sy = sbs, sz = sbs, sw = sbs;
#pragma unroll
        for (int c = 0; c < 8; ++c) {
            const float ws = sws[c];
            sx = fmaf(ws, fmaxf(acc1[c].x, 0.f), sx);
            sy = fmaf(ws, fmaxf(acc1[c].y, 0.f), sy);
            sz = fmaf(ws, fmaxf(acc1[c].z, 0.f), sz);
            sw = fmaf(ws, fmaxf(acc1[c].w, 0.f), sw);
        }

        float4 r; r.x = sx; r.y = sy; r.z = sz; r.w = sw;
        // q*4 == ty*SW + tx0 : aligned float4 LDS store, conflict-free
        *reinterpret_cast<float4*>(&sms[q * 4]) = r;
    }

    __syncthreads();

    // ---- phase 2: 9-neighbor aggregation, dilations 2 (narrow) & 4 (wide)
    const float* offb = offset + (size_t)b * 18 * HW;
    const float* wtb  = weight + (size_t)b * HW;
    float* outb = out + (size_t)(b * Dc + d) * HW;

#pragma unroll 1
    for (int k = 0; k < 3; ++k) {           // 2*512 + 256 = 1280 = TH*TW
        const int idx = k * 512 + tid;
        if (idx < TH * TW) {
            const int oy  = idx / TW;
            const int ox  = idx - oy * TW;
            const int hw  = (h0t + oy) * Wc + (w0t + ox);

            float off[18];
#pragma unroll
            for (int s = 0; s < 18; ++s)
                off[s] = offb[s * HW + hw];
            const float wt = wtb[hw] * 0.5f;

            const float* sp = sms + (oy + R) * SW + (ox + R);
            float a = 0.f;
#pragma unroll
            for (int s = 0; s < 9; ++s) {
                const int dy = s / 3 - 1, dx = s % 3 - 1;
                a = fmaf(off[s + 9], sp[(dy * 2) * SW + dx * 2],
                    fmaf(off[s],     sp[(dy * 4) * SW + dx * 4], a));
            }
            outb[hw] = a * wt;
        }
    }
}

extern "C" void kernel_launch(void* const* d_in, const int* in_sizes, int n_in,
                              void* d_out, int out_size, void* d_ws, size_t ws_size,
                              hipStream_t stream)
{
    const float* x1     = (const float*)d_in[0];
    const float* offset = (const float*)d_in[1];
    const float* weight = (const float*)d_in[2];
    const float* w0     = (const float*)d_in[3];
    const float* s0     = (const float*)d_in[4];
    const float* b0     = (const float*)d_in[5];
    const float* w1     = (const float*)d_in[6];
    const float* s1     = (const float*)d_in[7];
    const float* b1     = (const float*)d_in[8];
    const float* wsim   = (const float*)d_in[9];
    const float* bsim   = (const float*)d_in[10];
    float* out = (float*)d_out;

    // B(2) * 16 tiles * D(32) = 1024 blocks x 512 threads, one fused pass
    fused_kernel<<<1024, 512, 0, stream>>>(x1, offset, weight,
                                           w0, s0, b0, w1, s1, b1, wsim, bsim,
                                           out);
}

// Round 7
// 120.041 us; speedup vs baseline: 2.4748x; 1.0163x over previous
//
#include <hip/hip_runtime.h>

#define Bc 2
#define Gc 8
#define Dc 32
#define Hc 128
#define Wc 160
#define HW (Hc * Wc)         // 20480
#define DHW (Dc * HW)        // 655360

// Fused tiling: one block = one (b, d, 32x40 output tile).
// sim computed with reflect halo R=4 into LDS, aggregation reads LDS only.
#define TH 32
#define TW 40
#define R  4
#define SH (TH + 2 * R)      // 40
#define SW (TW + 2 * R)      // 48
#define SIMN (SH * SW)       // 1920
#define NQ (SIMN / 4)        // 480 float4-quads
#define QPR (SW / 4)         // 12 quads per sim-tile row
#define NQ2 (TH * TW / 4)    // 320 output quads (phase 2)
#define QPR2 (TW / 4)        // 10 output quads per row

// Register-pressure history (measured): all caps (84/64/128) spill; no-cap
// straight-line phase 1 (one quad/thread, 512-thread block) is the only
// healthy config (~38us kernel). Do NOT reintroduce loops or caps in phase 1.
__global__ __launch_bounds__(512)
void fused_kernel(
    const float* __restrict__ x1, const float* __restrict__ offset,
    const float* __restrict__ weight,
    const float* __restrict__ w0, const float* __restrict__ s0, const float* __restrict__ b0,
    const float* __restrict__ w1, const float* __restrict__ s1, const float* __restrict__ b1,
    const float* __restrict__ wsim, const float* __restrict__ bsim,
    float* __restrict__ out)
{
    __shared__ __align__(16) float sms[SIMN];  // sim tile with halo
    __shared__ float smw[289];                 // folded MLP weights
    const int tid = threadIdx.x;

    // stage BN-folded weights (single pass, tid<289)
    if (tid < 289) {
        const int i = tid;
        float v;
        if (i < 128)      v = w0[i] * s0[i >> 3];                 // w0f[o][g]
        else if (i < 144) v = b0[i - 128];
        else if (i < 272) v = w1[i - 144] * s1[(i - 144) >> 4];   // w1f[c][o]
        else if (i < 280) v = b1[i - 272];
        else if (i < 288) v = wsim[i - 280];
        else              v = bsim[0];
        smw[i] = v;
    }

    // blk = b*512 + tile*32 + d  (d innermost: consecutive blocks share the
    // offset/weight tile in L2; tile-neighbors are +32/+128 blocks = same XCD)
    const int blk = blockIdx.x;              // 1024 blocks
    const int d   = blk & 31;
    const int t   = (blk >> 5) & 15;
    const int b   = blk >> 9;
    const int h0t = (t >> 2) * TH;
    const int w0t = (t & 3) * TW;

    __syncthreads();

    const float* sw0 = smw;
    const float* sb0 = smw + 128;
    const float* sw1 = smw + 144;
    const float* sb1 = smw + 272;
    const float* sws = smw + 280;
    const float  sbs = smw[288];

    const float* xb = x1 + (size_t)b * (Gc * DHW) + (size_t)d * HW;

    // ---- phase 1: MLP 8->16->8->1 into the LDS sim tile (incl. reflect halo)
    // ONE quad per thread, straight-line (proven no-spill structure).
    if (tid < NQ) {
        const int q   = tid;
        const int ty  = q / QPR;
        const int tx0 = (q - ty * QPR) * 4;
        int gh = h0t - R + ty;
        gh = gh < 0 ? -gh : (gh >= Hc ? 2 * Hc - 2 - gh : gh);
        const int gw0 = w0t - R + tx0;

        float4 xv[Gc];
        if (gw0 >= 0 && gw0 <= Wc - 4) {
            const float* p = xb + gh * Wc + gw0;
#pragma unroll
            for (int g = 0; g < Gc; ++g)
                xv[g] = *reinterpret_cast<const float4*>(p + g * DHW);
        } else {
            int gw[4];
#pragma unroll
            for (int j = 0; j < 4; ++j) {
                int x = gw0 + j;
                gw[j] = x < 0 ? -x : (x >= Wc ? 2 * Wc - 2 - x : x);
            }
            const float* p = xb + gh * Wc;
#pragma unroll
            for (int g = 0; g < Gc; ++g) {
                xv[g].x = p[g * DHW + gw[0]];
                xv[g].y = p[g * DHW + gw[1]];
                xv[g].z = p[g * DHW + gw[2]];
                xv[g].w = p[g * DHW + gw[3]];
            }
        }

        float4 acc1[8];
#pragma unroll
        for (int c = 0; c < 8; ++c) {
            const float bb = sb1[c];
            acc1[c].x = bb; acc1[c].y = bb; acc1[c].z = bb; acc1[c].w = bb;
        }

#pragma unroll
        for (int o = 0; o < 16; ++o) {
            float ax = sb0[o], ay = ax, az = ax, aw = ax;
#pragma unroll
            for (int g = 0; g < Gc; ++g) {
                const float wv = sw0[o * Gc + g];
                ax = fmaf(wv, xv[g].x, ax);
                ay = fmaf(wv, xv[g].y, ay);
                az = fmaf(wv, xv[g].z, az);
                aw = fmaf(wv, xv[g].w, aw);
            }
            ax = fmaxf(ax, 0.f);
            ay = fmaxf(ay, 0.f);
            az = fmaxf(az, 0.f);
            aw = fmaxf(aw, 0.f);
#pragma unroll
            for (int c = 0; c < 8; ++c) {
                const float wv = sw1[c * 16 + o];
                acc1[c].x = fmaf(wv, ax, acc1[c].x);
                acc1[c].y = fmaf(wv, ay, acc1[c].y);
                acc1[c].z = fmaf(wv, az, acc1[c].z);
                acc1[c].w = fmaf(wv, aw, acc1[c].w);
            }
        }

        float sx = sbs, sy = sbs, sz = sbs, sw = sbs;
#pragma unroll
        for (int c = 0; c < 8; ++c) {
            const float ws = sws[c];
            sx = fmaf(ws, fmaxf(acc1[c].x, 0.f), sx);
            sy = fmaf(ws, fmaxf(acc1[c].y, 0.f), sy);
            sz = fmaf(ws, fmaxf(acc1[c].z, 0.f), sz);
            sw = fmaf(ws, fmaxf(acc1[c].w, 0.f), sw);
        }

        float4 r; r.x = sx; r.y = sy; r.z = sz; r.w = sw;
        *reinterpret_cast<float4*>(&sms[q * 4]) = r;
    }

    // ---- async-split prefetch (T14): offset/weight loads for phase 2 do NOT
    // depend on the LDS tile -> issue BEFORE the barrier so their ~L2 latency
    // hides under the barrier wait. sched_barrier(0) keeps the register
    // allocator from hoisting these into the MLP's live range.
    __builtin_amdgcn_sched_barrier(0);

    // phase 2 mapping: one thread = 4 consecutive w-pixels (float4 everywhere)
    const int oy  = tid / QPR2;              // valid for tid < NQ2
    const int ox  = (tid - oy * QPR2) * 4;   // multiple of 4
    const int hw4 = (h0t + oy) * Wc + (w0t + ox);

    float4 off4[18];
    float4 wt4;
    if (tid < NQ2) {
        const float* offb = offset + (size_t)b * 18 * HW;
#pragma unroll
        for (int s = 0; s < 18; ++s)
            off4[s] = *reinterpret_cast<const float4*>(offb + s * HW + hw4);
        wt4 = *reinterpret_cast<const float4*>(weight + (size_t)b * HW + hw4);
    }

    __syncthreads();

    // ---- phase 2: 9-neighbor aggregation, dilations 2 (narrow) & 4 (wide)
    if (tid < NQ2) {
        // sp is 16B-aligned: (oy+R)*SW is a multiple of 4 floats (SW=48),
        // ox+R is a multiple of 4. Wide taps (dx*4) stay 16B-aligned float4;
        // narrow taps (dx*2) are 8B-aligned -> two float2 reads.
        const float* sp = sms + (oy + R) * SW + (ox + R);
        float ax = 0.f, ay = 0.f, az = 0.f, aw = 0.f;
#pragma unroll
        for (int s = 0; s < 9; ++s) {
            const int dy = s / 3 - 1, dx = s % 3 - 1;
            const float4 cw = *reinterpret_cast<const float4*>(sp + dy * 4 * SW + dx * 4);
            const float* np = sp + dy * 2 * SW + dx * 2;
            const float2 n0 = *reinterpret_cast<const float2*>(np);
            const float2 n1 = *reinterpret_cast<const float2*>(np + 2);
            const float4 ow = off4[s];       // wide weights (4 pixels)
            const float4 on = off4[s + 9];   // narrow weights (4 pixels)
            ax = fmaf(on.x, n0.x, fmaf(ow.x, cw.x, ax));
            ay = fmaf(on.y, n0.y, fmaf(ow.y, cw.y, ay));
            az = fmaf(on.z, n1.x, fmaf(ow.z, cw.z, az));
            aw = fmaf(on.w, n1.y, fmaf(ow.w, cw.w, aw));
        }
        float4 r;
        r.x = ax * 0.5f * wt4.x;
        r.y = ay * 0.5f * wt4.y;
        r.z = az * 0.5f * wt4.z;
        r.w = aw * 0.5f * wt4.w;
        float* outb = out + (size_t)(b * Dc + d) * HW;
        *reinterpret_cast<float4*>(outb + hw4) = r;
    }
}

extern "C" void kernel_launch(void* const* d_in, const int* in_sizes, int n_in,
                              void* d_out, int out_size, void* d_ws, size_t ws_size,
                              hipStream_t stream)
{
    const float* x1     = (const float*)d_in[0];
    const float* offset = (const float*)d_in[1];
    const float* weight = (const float*)d_in[2];
    const float* w0     = (const float*)d_in[3];
    const float* s0     = (const float*)d_in[4];
    const float* b0     = (const float*)d_in[5];
    const float* w1     = (const float*)d_in[6];
    const float* s1     = (const float*)d_in[7];
    const float* b1     = (const float*)d_in[8];
    const float* wsim   = (const float*)d_in[9];
    const float* bsim   = (const float*)d_in[10];
    float* out = (float*)d_out;

    // B(2) * 16 tiles * D(32) = 1024 blocks x 512 threads, one fused pass
    fused_kernel<<<1024, 512, 0, stream>>>(x1, offset, weight,
                                           w0, s0, b0, w1, s1, b1, wsim, bsim,
                                           out);
}

// Round 9
// 115.398 us; speedup vs baseline: 2.5744x; 1.0402x over previous
//
#include <hip/hip_runtime.h>

#define Bc 2
#define Gc 8
#define Dc 32
#define Hc 128
#define Wc 160
#define HW (Hc * Wc)         // 20480
#define DHW (Dc * HW)        // 655360

// ---------------------------------------------------------------------------
// Kernel A: per-point MLP 8 -> 16 -> 8 -> 1 (BN folded into LDS weights).
// One thread = one float4 quad of w-points, STRAIGHT-LINE body (no q-loop:
// rounds 1-5 proved any loop here invites pipelining -> 208+ VGPR or spill),
// interleaved layer0/layer1 accumulators (no h0[16] array, ~80 live VGPR).
// No halo, no recompute: every point computed exactly once (vs fused 1.5x).
// ---------------------------------------------------------------------------
__global__ __launch_bounds__(256) void mlp_kernel(
    const float* __restrict__ x1,
    const float* __restrict__ w0, const float* __restrict__ s0, const float* __restrict__ b0,
    const float* __restrict__ w1, const float* __restrict__ s1, const float* __restrict__ b1,
    const float* __restrict__ wsim, const float* __restrict__ bsim,
    float* __restrict__ sim)
{
    __shared__ float smw[289];
    const int tid = threadIdx.x;
    for (int i = tid; i < 289; i += 256) {
        float v;
        if (i < 128)      v = w0[i] * s0[i >> 3];                 // w0f[o][g]
        else if (i < 144) v = b0[i - 128];
        else if (i < 272) v = w1[i - 144] * s1[(i - 144) >> 4];   // w1f[c][o]
        else if (i < 280) v = b1[i - 272];
        else if (i < 288) v = wsim[i - 280];
        else              v = bsim[0];
        smw[i] = v;
    }
    __syncthreads();
    const float* sw0 = smw;
    const float* sb0 = smw + 128;
    const float* sw1 = smw + 144;
    const float* sb1 = smw + 272;
    const float* sws = smw + 280;
    const float  sbs = smw[288];

    const int t   = blockIdx.x * 256 + tid;   // 0 .. 327679 (exact grid)
    const int p   = t << 2;                   // base point over (b,d,h,w)
    const int b   = p / DHW;
    const int dhw = p - b * DHW;
    const float* xb = x1 + (size_t)b * (Gc * DHW) + dhw;

    float4 xv[Gc];
#pragma unroll
    for (int g = 0; g < Gc; ++g)
        xv[g] = *reinterpret_cast<const float4*>(xb + g * DHW);

    // layer-1 accumulators seeded with bias1 (8 x float4 = 32 regs)
    float4 acc1[8];
#pragma unroll
    for (int c = 0; c < 8; ++c) {
        const float bb = sb1[c];
        acc1[c].x = bb; acc1[c].y = bb; acc1[c].z = bb; acc1[c].w = bb;
    }

    // layer 0 fused into layer 1: h0[o] consumed immediately (never an array)
#pragma unroll
    for (int o = 0; o < 16; ++o) {
        float ax = sb0[o], ay = ax, az = ax, aw = ax;
#pragma unroll
        for (int g = 0; g < Gc; ++g) {
            const float wv = sw0[o * Gc + g];
            ax = fmaf(wv, xv[g].x, ax);
            ay = fmaf(wv, xv[g].y, ay);
            az = fmaf(wv, xv[g].z, az);
            aw = fmaf(wv, xv[g].w, aw);
        }
        ax = fmaxf(ax, 0.f);
        ay = fmaxf(ay, 0.f);
        az = fmaxf(az, 0.f);
        aw = fmaxf(aw, 0.f);
#pragma unroll
        for (int c = 0; c < 8; ++c) {
            const float wv = sw1[c * 16 + o];
            acc1[c].x = fmaf(wv, ax, acc1[c].x);
            acc1[c].y = fmaf(wv, ay, acc1[c].y);
            acc1[c].z = fmaf(wv, az, acc1[c].z);
            acc1[c].w = fmaf(wv, aw, acc1[c].w);
        }
    }

    // sim projection 8 -> 1
    float sx = sbs, sy = sbs, sz = sbs, sw = sbs;
#pragma unroll
    for (int c = 0; c < 8; ++c) {
        const float ws = sws[c];
        sx = fmaf(ws, fmaxf(acc1[c].x, 0.f), sx);
        sy = fmaf(ws, fmaxf(acc1[c].y, 0.f), sy);
        sz = fmaf(ws, fmaxf(acc1[c].z, 0.f), sz);
        sw = fmaf(ws, fmaxf(acc1[c].w, 0.f), sw);
    }

    float4 r; r.x = sx; r.y = sy; r.z = sz; r.w = sw;
    *reinterpret_cast<float4*>(sim + p) = r;
}

// ---------------------------------------------------------------------------
// Kernel B: 9-neighbor aggregation, dilations 2 (narrow) & 4 (wide), reflect
// padding, * 0.5 * weight. One thread = one (b,d,h, 4-wide w quad).
// TOTAL QUADS = B*D*H*(W/4) = 327680 -> grid 1280x256 EXACT.
// (Round-8 crash: launched 2560 blocks = 2x -> threads decoded b in {2,3}
//  -> OOB writes. Grid must equal the quad count.)
// sim is L2-warm from kernel A (5.25 MB, no inter-kernel cache flush).
// Vector loads throughout; scalar reflect fallback only for the 2 edge
// w-columns (w4==0 / w4==156). Low VGPR -> deep latency hiding.
// ---------------------------------------------------------------------------
__global__ __launch_bounds__(256) void agg_kernel(
    const float* __restrict__ sim, const float* __restrict__ offset,
    const float* __restrict__ weight, float* __restrict__ out)
{
    const int l  = blockIdx.x * 256 + threadIdx.x;  // 0 .. 327679 (exact)
    const int q  = l % (Wc / 4);
    const int w4 = q * 4;
    int r = l / (Wc / 4);
    const int h = r % Hc;
    r /= Hc;
    const int d = r & 31;
    const int b = r >> 5;                           // 0..1
    const int hw4 = h * Wc + w4;

    // offsets + weight: 19 vector loads for 4 output pixels
    const float* offb = offset + (size_t)b * 18 * HW;
    float4 off4[18];
#pragma unroll
    for (int s = 0; s < 18; ++s)
        off4[s] = *reinterpret_cast<const float4*>(offb + s * HW + hw4);
    float4 wt4 = *reinterpret_cast<const float4*>(weight + (size_t)b * HW + hw4);
    wt4.x *= 0.5f; wt4.y *= 0.5f; wt4.z *= 0.5f; wt4.w *= 0.5f;

    // reflected row indices (y only: vector loads stay row-contiguous)
    int y1[3], y2[3];
#pragma unroll
    for (int iy = 0; iy < 3; ++iy) {
        int a1 = h + (iy - 1) * 2; y1[iy] = a1 < 0 ? -a1 : (a1 >= Hc ? 2 * Hc - 2 - a1 : a1);
        int a2 = h + (iy - 1) * 4; y2[iy] = a2 < 0 ? -a2 : (a2 >= Hc ? 2 * Hc - 2 - a2 : a2);
    }

    const float* sp = sim + (size_t)(b * Dc + d) * HW;
    float ax = 0.f, ay = 0.f, az = 0.f, aw = 0.f;

    if (w4 >= 4 && w4 <= Wc - 8) {
        // interior: wide taps 16B-aligned float4; narrow taps two 8B float2
#pragma unroll
        for (int s = 0; s < 9; ++s) {
            const int iy = s / 3, ix = s % 3;
            const float4 cw = *reinterpret_cast<const float4*>(
                sp + y2[iy] * Wc + w4 + (ix - 1) * 4);
            const float* np = sp + y1[iy] * Wc + w4 + (ix - 1) * 2;
            const float2 n0 = *reinterpret_cast<const float2*>(np);
            const float2 n1 = *reinterpret_cast<const float2*>(np + 2);
            const float4 ow = off4[s];
            const float4 on = off4[s + 9];
            ax = fmaf(on.x, n0.x, fmaf(ow.x, cw.x, ax));
            ay = fmaf(on.y, n0.y, fmaf(ow.y, cw.y, ay));
            az = fmaf(on.z, n1.x, fmaf(ow.z, cw.z, az));
            aw = fmaf(on.w, n1.y, fmaf(ow.w, cw.w, aw));
        }
    } else {
        // edge quad (w4==0 or w4==Wc-4): scalar gathers with x-reflect
        float acc[4] = {0.f, 0.f, 0.f, 0.f};
#pragma unroll
        for (int j = 0; j < 4; ++j) {
            const int w = w4 + j;
            float a = 0.f;
#pragma unroll
            for (int s = 0; s < 9; ++s) {
                const int iy = s / 3, ix = s % 3;
                int x1c = w + (ix - 1) * 2; x1c = x1c < 0 ? -x1c : (x1c >= Wc ? 2 * Wc - 2 - x1c : x1c);
                int x2c = w + (ix - 1) * 4; x2c = x2c < 0 ? -x2c : (x2c >= Wc ? 2 * Wc - 2 - x2c : x2c);
                const float on = j == 0 ? off4[s + 9].x : j == 1 ? off4[s + 9].y : j == 2 ? off4[s + 9].z : off4[s + 9].w;
                const float ow = j == 0 ? off4[s].x     : j == 1 ? off4[s].y     : j == 2 ? off4[s].z     : off4[s].w;
                a = fmaf(on, sp[y1[iy] * Wc + x1c], fmaf(ow, sp[y2[iy] * Wc + x2c], a));
            }
            acc[j] = a;
        }
        ax = acc[0]; ay = acc[1]; az = acc[2]; aw = acc[3];
    }

    float4 o4;
    o4.x = ax * wt4.x;
    o4.y = ay * wt4.y;
    o4.z = az * wt4.z;
    o4.w = aw * wt4.w;
    float* outb = out + (size_t)(b * Dc + d) * HW;
    *reinterpret_cast<float4*>(outb + hw4) = o4;
}

extern "C" void kernel_launch(void* const* d_in, const int* in_sizes, int n_in,
                              void* d_out, int out_size, void* d_ws, size_t ws_size,
                              hipStream_t stream)
{
    const float* x1     = (const float*)d_in[0];
    const float* offset = (const float*)d_in[1];
    const float* weight = (const float*)d_in[2];
    const float* w0     = (const float*)d_in[3];
    const float* s0     = (const float*)d_in[4];
    const float* b0     = (const float*)d_in[5];
    const float* w1     = (const float*)d_in[6];
    const float* s1     = (const float*)d_in[7];
    const float* b1     = (const float*)d_in[8];
    const float* wsim   = (const float*)d_in[9];
    const float* bsim   = (const float*)d_in[10];
    float* out = (float*)d_out;
    float* sim = (float*)d_ws;   // B*D*H*W floats = 5.25 MB scratch

    // 327680 point-quads / 256 = 1280 blocks (exact)
    mlp_kernel<<<1280, 256, 0, stream>>>(x1, w0, s0, b0, w1, s1, b1, wsim, bsim, sim);
    // 327680 output-quads / 256 = 1280 blocks (exact)
    agg_kernel<<<1280, 256, 0, stream>>>(sim, offset, weight, out);
}